// Round 1
// baseline (772.410 us; speedup 1.0000x reference)
//
#include <hip/hip_runtime.h>
#include <math.h>

// GConvLSTM fused kernel, fp32, one thread per node.
// Outputs concatenated: y [N,9] | h0 [N,32] | c0 [N,32]
// edge_index / edge_weight are mathematically unused (ChebConv K=1) -> never read.

#define HD 32
#define FD 8
#define BLK 256

struct Params {
    const float* __restrict__ x;
    const float* __restrict__ h;
    const float* __restrict__ c;
    const float* __restrict__ Wx[4];   // i,f,c,o  each [8][32]
    const float* __restrict__ bx[4];
    const float* __restrict__ Wh[4];   // each [32][32]
    const float* __restrict__ bh[4];
    const float* __restrict__ b[4];
    const float* __restrict__ wci;
    const float* __restrict__ wcf;
    const float* __restrict__ wco;
    const float* __restrict__ Wl;      // [32][9]
    const float* __restrict__ bl;      // [9]
    float* __restrict__ y;             // [N,9]
    float* __restrict__ h0;            // [N,32]
    float* __restrict__ c0;            // [N,32]
    int N;
};

__device__ __forceinline__ float rcp_f(float x) { return __builtin_amdgcn_rcpf(x); }
__device__ __forceinline__ float fsigmoid(float x) { return rcp_f(1.0f + __expf(-x)); }
__device__ __forceinline__ float ftanh(float x) {
    // tanh(x) = sign(x) * (1 - 2/(exp(2|x|)+1)); exp overflow -> inf -> rcp -> 0 -> 1 (safe)
    float e = __expf(2.0f * fabsf(x));
    float r = 1.0f - 2.0f * rcp_f(1.0f + e);
    return copysignf(r, x);
}

__global__ __launch_bounds__(BLK) void gconvlstm_kernel(Params p) {
    // Transposed weights in LDS; all reads are wave-uniform (broadcast).
    __shared__ __align__(16) float WXT[4][HD][FD];    // [gate][j][k] = Wx[k][j]
    __shared__ __align__(16) float WHT[4][HD][HD];    // [gate][j][k] = Wh[k][j]
    __shared__ __align__(16) float WLT[HD][12];       // [j][m], m<9 valid, padded
    __shared__ __align__(16) float SCV[HD][8];        // [j][Bi,Bf,Bc,Bo,wci,wcf,wco,0]

    const int tid = threadIdx.x;

    for (int t = tid; t < 4 * HD * FD; t += BLK) {
        int g = t >> 8, r = t & 255, j = r >> 3, k = r & 7;
        WXT[g][j][k] = p.Wx[g][k * HD + j];
    }
    for (int t = tid; t < 4 * HD * HD; t += BLK) {
        int g = t >> 10, r = t & 1023, j = r >> 5, k = r & 31;
        WHT[g][j][k] = p.Wh[g][k * HD + j];
    }
    for (int t = tid; t < HD * 12; t += BLK) {
        int j = t / 12, m = t - j * 12;
        WLT[j][m] = (m < 9) ? p.Wl[j * 9 + m] : 0.0f;
    }
    for (int t = tid; t < HD * 8; t += BLK) {
        int j = t >> 3, s = t & 7;
        float v = 0.0f;
        if (s < 4)      v = p.bx[s][j] + p.bh[s][j] + p.b[s][j];
        else if (s == 4) v = p.wci[j];
        else if (s == 5) v = p.wcf[j];
        else if (s == 6) v = p.wco[j];
        SCV[j][s] = v;
    }
    __syncthreads();

    const int n = blockIdx.x * BLK + tid;
    if (n >= p.N) return;

    float xv[FD], hv[HD], cv[HD], h0a[HD];

    const float4* xp = reinterpret_cast<const float4*>(p.x + (size_t)n * FD);
    reinterpret_cast<float4*>(xv)[0] = xp[0];
    reinterpret_cast<float4*>(xv)[1] = xp[1];
    const float4* hp = reinterpret_cast<const float4*>(p.h + (size_t)n * HD);
#pragma unroll
    for (int q = 0; q < 8; ++q) reinterpret_cast<float4*>(hv)[q] = hp[q];
    const float4* cp = reinterpret_cast<const float4*>(p.c + (size_t)n * HD);
#pragma unroll
    for (int q = 0; q < 8; ++q) reinterpret_cast<float4*>(cv)[q] = cp[q];

    float yacc[9];
#pragma unroll
    for (int m = 0; m < 9; ++m) yacc[m] = p.bl[m];  // uniform -> s_load

#pragma unroll
    for (int j = 0; j < HD; ++j) {
        float ai = 0.f, af = 0.f, at = 0.f, ao = 0.f;
#pragma unroll
        for (int k = 0; k < FD; ++k) {
            ai += xv[k] * WXT[0][j][k];
            af += xv[k] * WXT[1][j][k];
            at += xv[k] * WXT[2][j][k];
            ao += xv[k] * WXT[3][j][k];
        }
#pragma unroll
        for (int k = 0; k < HD; ++k) {
            ai += hv[k] * WHT[0][j][k];
            af += hv[k] * WHT[1][j][k];
            at += hv[k] * WHT[2][j][k];
            ao += hv[k] * WHT[3][j][k];
        }
        const float cj = cv[j];
        const float pi = ai + SCV[j][0] + SCV[j][4] * cj;
        const float pf = af + SCV[j][1] + SCV[j][5] * cj;
        const float pt = at + SCV[j][2];
        const float ig = fsigmoid(pi);
        const float fg = fsigmoid(pf);
        const float tg = ftanh(pt);
        const float c0 = fg * cj + ig * tg;
        const float po = ao + SCV[j][3] + SCV[j][6] * c0;
        const float og = fsigmoid(po);
        const float h0 = og * ftanh(c0);
        cv[j] = c0;      // reuse c registers as the c0 store buffer
        h0a[j] = h0;
        const float rh = fmaxf(h0, 0.0f);
#pragma unroll
        for (int m = 0; m < 9; ++m) yacc[m] += rh * WLT[j][m];
    }

    float* yo = p.y + (size_t)n * 9;
#pragma unroll
    for (int m = 0; m < 9; ++m) yo[m] = yacc[m];
    float4* ho = reinterpret_cast<float4*>(p.h0 + (size_t)n * HD);
#pragma unroll
    for (int q = 0; q < 8; ++q) ho[q] = reinterpret_cast<const float4*>(h0a)[q];
    float4* co = reinterpret_cast<float4*>(p.c0 + (size_t)n * HD);
#pragma unroll
    for (int q = 0; q < 8; ++q) co[q] = reinterpret_cast<const float4*>(cv)[q];
}

extern "C" void kernel_launch(void* const* d_in, const int* in_sizes, int n_in,
                              void* d_out, int out_size, void* d_ws, size_t ws_size,
                              hipStream_t stream) {
    (void)n_in; (void)d_ws; (void)ws_size;
    const int N = in_sizes[0] / FD;   // x is [N,8]

    Params p;
    p.x = (const float*)d_in[0];
    // d_in[1] = edge_index (int64), d_in[2] = edge_weight -- unused (ChebConv K=1)
    p.h = (const float*)d_in[3];
    p.c = (const float*)d_in[4];

    // gate blocks: i:5-10, f:11-16, c:17-21 (no peephole), o:22-27
    const int wx_i[4] = {5, 11, 17, 22};
    const int bx_i[4] = {6, 12, 18, 23};
    const int wh_i[4] = {7, 13, 19, 24};
    const int bh_i[4] = {8, 14, 20, 25};
    const int b_i[4]  = {9, 15, 21, 26};
    for (int g = 0; g < 4; ++g) {
        p.Wx[g] = (const float*)d_in[wx_i[g]];
        p.bx[g] = (const float*)d_in[bx_i[g]];
        p.Wh[g] = (const float*)d_in[wh_i[g]];
        p.bh[g] = (const float*)d_in[bh_i[g]];
        p.b[g]  = (const float*)d_in[b_i[g]];
    }
    p.wci = (const float*)d_in[10];
    p.wcf = (const float*)d_in[16];
    p.wco = (const float*)d_in[27];
    p.Wl  = (const float*)d_in[28];
    p.bl  = (const float*)d_in[29];

    float* out = (float*)d_out;
    p.y  = out;                        // [N,9]
    p.h0 = out + (size_t)9 * N;        // [N,32]
    p.c0 = out + (size_t)41 * N;       // [N,32]
    p.N  = N;

    const int blocks = (N + BLK - 1) / BLK;
    gconvlstm_kernel<<<blocks, BLK, 0, stream>>>(p);
}